// Round 1
// baseline (2909.367 us; speedup 1.0000x reference)
//
#include <hip/hip_runtime.h>
#include <math.h>

#define HW 65536
#define IMG 256
#define NS 5
#define DFEAT 128
#define CMID 64
#define TEMPER 0.1f
#define BNEPS 1e-5f

// ---------------------------------------------------------------- zero
__global__ void zero_kernel(float* __restrict__ p, int n) {
  int i = blockIdx.x * blockDim.x + threadIdx.x;
  if (i < n) p[i] = 0.f;
}

// ---------------------------------------------------------------- conv3x3 + per-(n,oc) stats
// grid: (16,16, 5*4)  block: 256.  Each block: 16x16 pixel tile, 16 output channels.
// Each thread: 1 pixel x 16 oc. Weights read with wave-uniform indices -> s_load.
template<int C>
__global__ __launch_bounds__(256) void conv_kernel(
    const float* __restrict__ x,    // [5][C][256][256]
    const float* __restrict__ w1,   // [64][C][3][3]
    float* __restrict__ h1,         // [5][64][HW]
    float* __restrict__ st)         // [5][64][2] (sum, sumsq) accumulators
{
  const int tid = threadIdx.x;
  const int n   = blockIdx.z >> 2;
  const int ocb = (blockIdx.z & 3) << 4;
  const int px  = (blockIdx.x << 4) + (tid & 15);
  const int py  = (blockIdx.y << 4) + (tid >> 4);

  float acc[16];
#pragma unroll
  for (int u = 0; u < 16; ++u) acc[u] = 0.f;

  const float* xn = x + (size_t)n * C * HW;
  for (int ic = 0; ic < C; ++ic) {
    const float* xc = xn + (size_t)ic * HW;
    float v[9];
#pragma unroll
    for (int dy = 0; dy < 3; ++dy) {
      int yy = py + dy - 1;
      bool yok = ((unsigned)yy < (unsigned)IMG);
      const float* row = xc + yy * IMG;
      v[dy * 3 + 0] = (yok && px > 0)       ? row[px - 1] : 0.f;
      v[dy * 3 + 1] = (yok)                 ? row[px]     : 0.f;
      v[dy * 3 + 2] = (yok && px < IMG - 1) ? row[px + 1] : 0.f;
    }
    const float* wb = w1 + ((size_t)ocb * C + ic) * 9;
#pragma unroll
    for (int u = 0; u < 16; ++u) {
      const float* w = wb + (size_t)u * C * 9;   // wave-uniform address -> scalar loads
      float s = w[0] * v[0];
#pragma unroll
      for (int k = 1; k < 9; ++k) s += w[k] * v[k];
      acc[u] += s;
    }
  }

  // store h1
  const size_t pix = (size_t)py * IMG + px;
  float* hp = h1 + ((size_t)n * CMID + ocb) * HW + pix;
#pragma unroll
  for (int u = 0; u < 16; ++u) hp[(size_t)u * HW] = acc[u];

  // block-reduce sum & sumsq per oc, one atomic pair per oc per block
  const int lane = tid & 63, wv = tid >> 6;
  __shared__ float reds[16][4], redq[16][4];
#pragma unroll
  for (int u = 0; u < 16; ++u) {
    float s = acc[u], q = acc[u] * acc[u];
    for (int off = 32; off; off >>= 1) {
      s += __shfl_down(s, off, 64);
      q += __shfl_down(q, off, 64);
    }
    if (lane == 0) { reds[u][wv] = s; redq[u][wv] = q; }
  }
  __syncthreads();
  if (tid < 16) {
    float s = reds[tid][0] + reds[tid][1] + reds[tid][2] + reds[tid][3];
    float q = redq[tid][0] + redq[tid][1] + redq[tid][2] + redq[tid][3];
    atomicAdd(&st[(n * CMID + ocb + tid) * 2 + 0], s);
    atomicAdd(&st[(n * CMID + ocb + tid) * 2 + 1], q);
  }
}

// ---------------------------------------------------------------- BN params from stats
// st: [5][nch][2]; batchmode=1 -> aggregate over samples (dense path)
__global__ void bn_param_kernel(const float* __restrict__ st,
                                const float* __restrict__ gamma,
                                const float* __restrict__ beta,
                                float* __restrict__ a, float* __restrict__ b,
                                int nch, int batchmode)
{
  int tid = threadIdx.x;
  if (tid >= NS * nch) return;
  int n = tid / nch, ch = tid % nch;
  float s, q, cnt;
  if (batchmode) {
    s = 0.f; q = 0.f;
    for (int m = 0; m < NS; ++m) { s += st[(m * nch + ch) * 2]; q += st[(m * nch + ch) * 2 + 1]; }
    cnt = (float)NS * (float)HW;
  } else {
    s = st[(n * nch + ch) * 2]; q = st[(n * nch + ch) * 2 + 1];
    cnt = (float)HW;
  }
  float mean = s / cnt;
  float var  = q / cnt - mean * mean;
  float inv  = rsqrtf(var + BNEPS);
  float av   = gamma[ch] * inv;
  a[n * nch + ch] = av;
  b[n * nch + ch] = beta[ch] - mean * av;
}

// ---------------------------------------------------------------- stage 2: bn1+relu -> 1x1(64->128)
// GAP=false: accumulate per-(n,o) sum & sumsq of h2 (for BN2 stats)
// GAP=true : apply BN2+relu, accumulate per-(n,o) GAP sums
// grid: (128, 5)  block 256.  512 pixels per block, tiles of 64.
template<bool GAP>
__global__ __launch_bounds__(256) void stage2_kernel(
    const float* __restrict__ h1,   // [5][64][HW]
    const float* __restrict__ w2,   // [128][64]
    const float* __restrict__ a1, const float* __restrict__ b1,   // [5][64]
    const float* __restrict__ a2, const float* __restrict__ b2,   // [5][128] (GAP only)
    float* __restrict__ out)        // [5][128][2] or [5][128]
{
  __shared__ float t[64 * 65];      // t[p][c], stride 65 (conflict-free)
  __shared__ float w2s[64 * 129];   // w2s[c][o], stride 129 (conflict-free)
  const int tid  = threadIdx.x;
  const int n    = blockIdx.y;
  const int pix0 = blockIdx.x * 512;

  for (int idx = tid; idx < DFEAT * CMID; idx += 256) {
    int o = idx >> 6, c = idx & 63;
    w2s[c * 129 + o] = w2[idx];
  }

  const int cl = tid >> 2;          // load-phase channel 0..63
  const int pq = tid & 3;           // load-phase pixel quarter
  const float a1c = a1[n * CMID + cl], b1c = b1[n * CMID + cl];
  const float* hbase = h1 + ((size_t)n * CMID + cl) * HW;

  const int og = tid & 31, pg = tid >> 5;   // compute phase: o = og+32r, pixels pg*8+j
  float a2v[4], b2v[4];
  if constexpr (GAP) {
#pragma unroll
    for (int r = 0; r < 4; ++r) {
      a2v[r] = a2[n * DFEAT + og + 32 * r];
      b2v[r] = b2[n * DFEAT + og + 32 * r];
    }
  }
  float rs[4] = {0, 0, 0, 0}, rq[4] = {0, 0, 0, 0};

  for (int tile = 0; tile < 8; ++tile) {
    const int pb = pix0 + tile * 64;
    __syncthreads();
    const float4* src = (const float4*)(hbase + pb + pq * 16);
#pragma unroll
    for (int q4 = 0; q4 < 4; ++q4) {
      float4 v = src[q4];
      int p = pq * 16 + q4 * 4;
      t[(p + 0) * 65 + cl] = fmaxf(a1c * v.x + b1c, 0.f);
      t[(p + 1) * 65 + cl] = fmaxf(a1c * v.y + b1c, 0.f);
      t[(p + 2) * 65 + cl] = fmaxf(a1c * v.z + b1c, 0.f);
      t[(p + 3) * 65 + cl] = fmaxf(a1c * v.w + b1c, 0.f);
    }
    __syncthreads();
    float acc[4][8];
#pragma unroll
    for (int r = 0; r < 4; ++r)
#pragma unroll
      for (int j = 0; j < 8; ++j) acc[r][j] = 0.f;
    for (int c = 0; c < 64; ++c) {
      float wv[4], tv[8];
#pragma unroll
      for (int r = 0; r < 4; ++r) wv[r] = w2s[c * 129 + og + 32 * r];
#pragma unroll
      for (int j = 0; j < 8; ++j) tv[j] = t[(pg * 8 + j) * 65 + c];
#pragma unroll
      for (int r = 0; r < 4; ++r)
#pragma unroll
        for (int j = 0; j < 8; ++j) acc[r][j] += wv[r] * tv[j];
    }
    if constexpr (GAP) {
#pragma unroll
      for (int r = 0; r < 4; ++r) {
        float s = 0.f;
#pragma unroll
        for (int j = 0; j < 8; ++j) s += fmaxf(a2v[r] * acc[r][j] + b2v[r], 0.f);
        rs[r] += s;
      }
    } else {
#pragma unroll
      for (int r = 0; r < 4; ++r) {
        float s = 0.f, q = 0.f;
#pragma unroll
        for (int j = 0; j < 8; ++j) { s += acc[r][j]; q += acc[r][j] * acc[r][j]; }
        rs[r] += s; rq[r] += q;
      }
    }
  }

  // reduce the 8 pixel-groups per output channel via LDS (reuse t)
  __syncthreads();
#pragma unroll
  for (int r = 0; r < 4; ++r) {
    t[(og + 32 * r) * 8 + pg] = rs[r];
    if constexpr (!GAP) t[1024 + (og + 32 * r) * 8 + pg] = rq[r];
  }
  __syncthreads();
  if (tid < DFEAT) {
    float s = 0.f;
    for (int p = 0; p < 8; ++p) s += t[tid * 8 + p];
    if constexpr (GAP) {
      atomicAdd(&out[n * DFEAT + tid], s);
    } else {
      float q = 0.f;
      for (int p = 0; p < 8; ++p) q += t[1024 + tid * 8 + p];
      atomicAdd(&out[(n * DFEAT + tid) * 2 + 0], s);
      atomicAdd(&out[(n * DFEAT + tid) * 2 + 1], q);
    }
  }
}

// ---------------------------------------------------------------- feature normalize
// grid 30 (= 6 encodes x 5 samples), block 128
__global__ void feat_kernel(const float* __restrict__ gap, float* __restrict__ QK) {
  int b = blockIdx.x;
  int e = b / 5, n = b % 5;
  int g = e >> 1, br = e & 1;
  int d = threadIdx.x;
  float v = gap[(e * 5 + n) * DFEAT + d] * (1.0f / (float)HW);
  float q = v * v;
  for (int off = 32; off; off >>= 1) q += __shfl_down(q, off, 64);
  __shared__ float r2[2];
  if ((d & 63) == 0) r2[d >> 6] = q;
  __syncthreads();
  float nrm = sqrtf(r2[0] + r2[1]);
  float inv = 1.0f / fmaxf(nrm, 1e-12f);
  QK[((br * 3 + g) * 5 + n) * DFEAT + d] = v * inv;
}

// ---------------------------------------------------------------- final loss
__global__ __launch_bounds__(256) void loss_kernel(const float* __restrict__ QK,
                                                   const int* __restrict__ dm,
                                                   float* __restrict__ out)
{
  __shared__ float Qs[1920], Ks[1920];
  __shared__ float S[75], X[45], cnt[15], ltab[15];
  const int tid = threadIdx.x;
  for (int i = tid; i < 1920; i += 256) { Qs[i] = QK[i]; Ks[i] = QK[1920 + i]; }
  if (tid < 15) cnt[tid] = 0.f;
  __syncthreads();
  if (tid < 75) {
    int g = tid / 25, i = (tid / 5) % 5, j = tid % 5;
    const float* q = &Qs[(g * 5 + i) * 128];
    const float* k = &Ks[(g * 5 + j) * 128];
    float s = 0.f;
    for (int d = 0; d < 128; ++d) s += q[d] * k[d];
    S[tid] = s;
  } else if (tid < 120) {
    int u = tid - 75;
    int g = u / 15, i = (u % 15) / 3, h = u % 3;
    const float* q = &Qs[(g * 5 + i) * 128];
    const float* k = &Ks[(h * 5 + i) * 128];
    float s = 0.f;
    for (int d = 0; d < 128; ++d) s += q[d] * k[d];
    X[u] = s;
  }
  {
    int a = tid >> 6, l = tid & 63;
    int c0 = 0, c1 = 0, c2 = 0;
    const int* base = dm + a * 16384;
    for (int k = 0; k < 256; ++k) {
      int v = base[k * 64 + l];
      c0 += (v == 1); c1 += (v == 2); c2 += (v == 3);
    }
    atomicAdd(&cnt[0 * 5 + a + 1], (float)c0);
    atomicAdd(&cnt[1 * 5 + a + 1], (float)c1);
    atomicAdd(&cnt[2 * 5 + a + 1], (float)c2);
  }
  __syncthreads();
  if (tid < 15) {
    int g = tid / 5, i = tid % 5;
    const float inv_t = 1.0f / TEMPER;
    float lg[9];
    lg[0] = S[g * 25 + i * 5 + i] * inv_t;
    for (int j = 0; j < 5; ++j) lg[1 + j] = (j == i) ? (-1e9f * inv_t) : S[g * 25 + i * 5 + j] * inv_t;
    for (int h = 0; h < 3; ++h) lg[6 + h] = (h == g) ? (-1e9f * inv_t) : X[g * 15 + i * 3 + h] * inv_t;
    float m = lg[0];
    for (int k = 1; k < 9; ++k) m = fmaxf(m, lg[k]);
    float se = 0.f;
    for (int k = 0; k < 9; ++k) se += expf(lg[k] - m);
    ltab[tid] = -lg[0] + m + logf(se);
  }
  __syncthreads();
  if (tid == 0) {
    float tot = 0.f, acc = 0.f;
    for (int k = 0; k < 15; ++k) { tot += cnt[k]; acc += cnt[k] * ltab[k]; }
    out[0] = (tot > 0.f) ? acc / fmaxf(tot, 1.f) : 0.f;
  }
}

// ---------------------------------------------------------------- host orchestration
extern "C" void kernel_launch(void* const* d_in, const int* in_sizes, int n_in,
                              void* d_out, int out_size, void* d_ws, size_t ws_size,
                              hipStream_t stream) {
  (void)in_sizes; (void)n_in; (void)out_size; (void)ws_size;

  const float* sp[3]  = {(const float*)d_in[0],  (const float*)d_in[8],  (const float*)d_in[16]};
  const float* dn[3]  = {(const float*)d_in[1],  (const float*)d_in[9],  (const float*)d_in[17]};
  const float* w1[3]  = {(const float*)d_in[2],  (const float*)d_in[10], (const float*)d_in[18]};
  const float* gm1[3] = {(const float*)d_in[3],  (const float*)d_in[11], (const float*)d_in[19]};
  const float* bt1[3] = {(const float*)d_in[4],  (const float*)d_in[12], (const float*)d_in[20]};
  const float* w2[3]  = {(const float*)d_in[5],  (const float*)d_in[13], (const float*)d_in[21]};
  const float* gm2[3] = {(const float*)d_in[6],  (const float*)d_in[14], (const float*)d_in[22]};
  const float* bt2[3] = {(const float*)d_in[7],  (const float*)d_in[15], (const float*)d_in[23]};
  const int*   dm     = (const int*)d_in[24];
  const int Cg[3] = {64, 32, 16};

  float* ws_f   = (float*)d_ws;
  float* h1     = ws_f;                    // [5][64][HW] = 20971520 floats (83.9 MB)
  float* stats1 = ws_f + 20971520;         // [6][5][64][2]  = 3840
  float* stats2 = stats1 + 3840;           // [6][5][128][2] = 7680
  float* gap    = stats2 + 7680;           // [6][5][128]    = 3840
  float* a1     = gap + 3840;              // [6][5][64]
  float* b1     = a1 + 1920;
  float* a2     = b1 + 1920;               // [6][5][128]
  float* b2     = a2 + 3840;
  float* QK     = b2 + 3840;               // [2][3][5][128] = 3840

  // zero the accumulator region (stats1+stats2+gap = 15360 floats)
  zero_kernel<<<60, 256, 0, stream>>>(stats1, 15360);

  for (int g = 0; g < 3; ++g) {
    for (int br = 0; br < 2; ++br) {
      const int e = g * 2 + br;
      const float* x = br ? dn[g] : sp[g];
      float* st1e = stats1 + e * 640;
      float* st2e = stats2 + e * 1280;
      float* gape = gap + e * 640;
      float* a1e = a1 + e * 320, *b1e = b1 + e * 320;
      float* a2e = a2 + e * 640, *b2e = b2 + e * 640;

      dim3 cg(16, 16, 20);
      if (Cg[g] == 64)      conv_kernel<64><<<cg, 256, 0, stream>>>(x, w1[g], h1, st1e);
      else if (Cg[g] == 32) conv_kernel<32><<<cg, 256, 0, stream>>>(x, w1[g], h1, st1e);
      else                  conv_kernel<16><<<cg, 256, 0, stream>>>(x, w1[g], h1, st1e);

      bn_param_kernel<<<1, 320, 0, stream>>>(st1e, gm1[g], bt1[g], a1e, b1e, CMID, br);

      dim3 sg(128, 5);
      stage2_kernel<false><<<sg, 256, 0, stream>>>(h1, w2[g], a1e, b1e, nullptr, nullptr, st2e);
      bn_param_kernel<<<1, 640, 0, stream>>>(st2e, gm2[g], bt2[g], a2e, b2e, DFEAT, br);
      stage2_kernel<true><<<sg, 256, 0, stream>>>(h1, w2[g], a1e, b1e, a2e, b2e, gape);
    }
  }

  feat_kernel<<<30, 128, 0, stream>>>(gap, QK);
  loss_kernel<<<1, 256, 0, stream>>>(QK, dm, (float*)d_out);
}

// Round 2
// 1308.746 us; speedup vs baseline: 2.2230x; 2.2230x over previous
//
#include <hip/hip_runtime.h>
#include <math.h>

#define HW 65536
#define NS 5
#define DFEAT 128
#define CMID 64
#define TEMPER 0.1f
#define BNEPS 1e-5f

typedef __attribute__((ext_vector_type(8))) short bf16x8;
typedef __attribute__((ext_vector_type(4))) float f32x4;

__device__ inline short f2bf(float f) {
  union { float f; unsigned u; } v; v.f = f;
  unsigned r = v.u + 0x7fffu + ((v.u >> 16) & 1u);
  return (short)(r >> 16);
}
__device__ inline float bf2f(unsigned short h) {
  union { unsigned u; float f; } v; v.u = ((unsigned)h) << 16;
  return v.f;
}

union U16B { int4 v; unsigned short s[8]; };

// ---------------------------------------------------------------- zero
__global__ void zero_kernel(float* __restrict__ p, int n) {
  int i = blockIdx.x * blockDim.x + threadIdx.x;
  if (i < n) p[i] = 0.f;
}

// ---------------------------------------------------------------- NCHW fp32 -> NHWC bf16 (pad C->CP with zeros)
template<int C, int CP>
__global__ __launch_bounds__(256) void transpose_kernel(const float* __restrict__ x,
                                                        unsigned short* __restrict__ xT) {
  __shared__ float t[64 * (CP + 1)];
  const int tid = threadIdx.x;
  const int n = blockIdx.y;
  const int pix0 = blockIdx.x * 64;
  const float* xn = x + (size_t)n * C * HW + pix0;
#pragma unroll
  for (int it = 0; it < CP * 64 / 256; ++it) {
    int idx = it * 256 + tid;
    int c = idx >> 6, pix = idx & 63;
    float v = (c < C) ? xn[(size_t)c * HW + pix] : 0.f;
    t[pix * (CP + 1) + c] = v;
  }
  __syncthreads();
  unsigned* out = (unsigned*)(xT + ((size_t)n * HW + pix0) * CP);
#pragma unroll
  for (int it = 0; it < 64 * CP / 2 / 256; ++it) {
    int idx = it * 256 + tid;
    int cp = idx & (CP / 2 - 1), pix = idx / (CP / 2);
    float f0 = t[pix * (CP + 1) + 2 * cp];
    float f1 = t[pix * (CP + 1) + 2 * cp + 1];
    unsigned u = ((unsigned)(unsigned short)f2bf(f0)) |
                 (((unsigned)(unsigned short)f2bf(f1)) << 16);
    out[pix * (CP / 2) + cp] = u;
  }
}

// ---------------------------------------------------------------- weight prep: fp32 -> bf16 hi/lo fragments
// w1p layout: [9 shift][KS][2 hl][64 n][32 kl]; w2p: [2 ks][2 hl][128 n][32 kl]
template<int C, int CP>
__global__ void wprep_kernel(const float* __restrict__ w1, const float* __restrict__ w2,
                             unsigned short* __restrict__ w1p, unsigned short* __restrict__ w2p) {
  const int KS = CP / 32;
  const int total1 = 9 * KS * 2 * 64 * 32;
  int idx = blockIdx.x * 256 + threadIdx.x;
  if (idx < total1) {
    int kl = idx & 31; int tmp = idx >> 5;
    int nn = tmp & 63; tmp >>= 6;
    int hl = tmp & 1;  tmp >>= 1;
    int ks = tmp % KS; int s = tmp / KS;
    int ic = ks * 32 + kl;
    float v = (ic < C) ? w1[((size_t)nn * C + ic) * 9 + s] : 0.f;
    short hi = f2bf(v);
    short r = (hl == 0) ? hi : f2bf(v - bf2f((unsigned short)hi));
    w1p[idx] = (unsigned short)r;
  } else if (idx < total1 + 2 * 2 * 128 * 32) {
    int i2 = idx - total1;
    int kl = i2 & 31;
    int nn = (i2 >> 5) & 127;
    int hl = (i2 >> 12) & 1;
    int ks = i2 >> 13;
    float v = w2[nn * 64 + ks * 32 + kl];
    short hi = f2bf(v);
    short r = (hl == 0) ? hi : f2bf(v - bf2f((unsigned short)hi));
    w2p[i2] = (unsigned short)r;
  }
}

// ---------------------------------------------------------------- conv3x3 via MFMA (implicit GEMM over 9 shifts)
// grid (8 tx, 32 ty, 5 n), block 256. Tile: 32x8 pixels x 64 oc.
// Also fuses per-(n,oc) BN1 stats; writes h1 NHWC bf16.
template<int CP>
__global__ __launch_bounds__(256, 2) void conv_mfma_kernel(
    const unsigned short* __restrict__ xT,   // [5][HW][CP] bf16
    const unsigned short* __restrict__ w1p,  // [9][KS][2][64][32] bf16
    unsigned short* __restrict__ h1,         // [5][HW][64] bf16
    float* __restrict__ st)                  // [5][64][2]
{
  const int KS = CP / 32;
  constexpr int XSB = 10 * 34 * CP * 2;      // staged input bytes
  constexpr int HSB = 256 * 72 * 2;          // store-transpose bytes
  constexpr int UNI = (XSB > HSB) ? XSB : HSB;
  __shared__ __align__(16) char smem[UNI];
  __shared__ float reds[4][64], redq[4][64];

  const int tid = threadIdx.x;
  const int lane = tid & 63, wave = tid >> 6;
  const int lanen = lane & 15, quad = lane >> 4;
  const int tx = blockIdx.x, ty = blockIdx.y, n = blockIdx.z;
  const int x0 = tx * 32, y0 = ty * 8;

  // ---- stage rows y0-1 .. y0+8, cols x0-1 .. x0+32 (34 px) of xT into smem
  unsigned short* xs = (unsigned short*)smem;
  const int ROWB = 34 * CP * 2;
  const int xstart = (tx == 0) ? 1 : 0;
  const int xend = (tx == 7) ? 33 : 34;
  for (int r = wave; r < 10; r += 4) {
    int gy = y0 - 1 + r;
    char* rowb = smem + r * ROWB;
    if ((unsigned)gy >= 256u) {
      for (int ofs = lane * 16; ofs < ROWB; ofs += 1024)
        *(int4*)(rowb + ofs) = make_int4(0, 0, 0, 0);
    } else {
      const char* g = (const char*)(xT + ((size_t)n * HW + gy * 256 + x0 - 1 + xstart) * CP);
      int nbytes = (xend - xstart) * CP * 2;
      char* dst = rowb + xstart * CP * 2;
      for (int ofs = lane * 16; ofs < nbytes; ofs += 1024)
        *(int4*)(dst + ofs) = *(const int4*)(g + ofs);
      if (xstart == 1) {
        for (int ofs = lane * 16; ofs < CP * 2; ofs += 1024)
          *(int4*)(rowb + ofs) = make_int4(0, 0, 0, 0);
      }
      if (xend == 33) {
        for (int ofs = lane * 16; ofs < CP * 2; ofs += 1024)
          *(int4*)(rowb + 33 * CP * 2 + ofs) = make_int4(0, 0, 0, 0);
      }
    }
  }
  __syncthreads();

  // ---- MFMA main loop
  f32x4 acc[4][4];
#pragma unroll
  for (int t = 0; t < 4; ++t)
#pragma unroll
    for (int nt = 0; nt < 4; ++nt)
      acc[t][nt] = (f32x4){0.f, 0.f, 0.f, 0.f};

  int pbase[4];
#pragma unroll
  for (int t = 0; t < 4; ++t) {
    int p = wave * 64 + t * 16 + lanen;
    pbase[t] = (p >> 5) * 34 + (p & 31);     // (py*34 + px)
  }

#pragma unroll
  for (int s = 0; s < 9; ++s) {
    const int dy = s / 3, dx = s % 3;
#pragma unroll
    for (int ks = 0; ks < KS; ++ks) {
      bf16x8 af[4];
#pragma unroll
      for (int t = 0; t < 4; ++t) {
        int eo = (pbase[t] + dy * 34 + dx) * CP + ks * 32 + quad * 8;
        af[t] = *(const bf16x8*)(xs + eo);
      }
#pragma unroll
      for (int hl = 0; hl < 2; ++hl) {
        const unsigned short* wb = w1p + ((((s * KS + ks) * 2 + hl) * 64) + lanen) * 32 + quad * 8;
#pragma unroll
        for (int nt = 0; nt < 4; ++nt) {
          bf16x8 bf = *(const bf16x8*)(wb + nt * 16 * 32);
#pragma unroll
          for (int t = 0; t < 4; ++t)
            acc[t][nt] = __builtin_amdgcn_mfma_f32_16x16x32_bf16(af[t], bf, acc[t][nt], 0, 0, 0);
        }
      }
    }
  }

  // ---- BN1 stats (sum, sumsq) per oc
#pragma unroll
  for (int nt = 0; nt < 4; ++nt) {
    float s = 0.f, q = 0.f;
#pragma unroll
    for (int t = 0; t < 4; ++t)
#pragma unroll
      for (int r = 0; r < 4; ++r) {
        float v = acc[t][nt][r];
        s += v; q += v * v;
      }
    s += __shfl_xor(s, 16); s += __shfl_xor(s, 32);
    q += __shfl_xor(q, 16); q += __shfl_xor(q, 32);
    if (lane < 16) { reds[wave][nt * 16 + lanen] = s; redq[wave][nt * 16 + lanen] = q; }
  }
  __syncthreads();
  if (tid < 64) {
    float s = reds[0][tid] + reds[1][tid] + reds[2][tid] + reds[3][tid];
    float q = redq[0][tid] + redq[1][tid] + redq[2][tid] + redq[3][tid];
    atomicAdd(&st[(n * 64 + tid) * 2 + 0], s);
    atomicAdd(&st[(n * 64 + tid) * 2 + 1], q);
  }

  // ---- store h1 NHWC via LDS transpose (reuse smem; all waves past K-loop per barrier above)
  unsigned short* hs = (unsigned short*)smem;
#pragma unroll
  for (int t = 0; t < 4; ++t)
#pragma unroll
    for (int nt = 0; nt < 4; ++nt)
#pragma unroll
      for (int r = 0; r < 4; ++r) {
        int pix = wave * 64 + t * 16 + quad * 4 + r;
        hs[pix * 72 + nt * 16 + lanen] = (unsigned short)f2bf(acc[t][nt][r]);
      }
  __syncthreads();
#pragma unroll
  for (int it = 0; it < 8; ++it) {
    int idx = it * 256 + tid;
    int ocg = idx & 7, pix = idx >> 3;
    int py = pix >> 5, px = pix & 31;
    int4 v = *(const int4*)(hs + pix * 72 + ocg * 8);
    *(int4*)(h1 + ((size_t)n * HW + (y0 + py) * 256 + x0 + px) * 64 + ocg * 8) = v;
  }
}

// ---------------------------------------------------------------- BN params from stats
__global__ void bn_param_kernel(const float* __restrict__ st,
                                const float* __restrict__ gamma,
                                const float* __restrict__ beta,
                                float* __restrict__ a, float* __restrict__ b,
                                int nch, int batchmode)
{
  int tid = threadIdx.x;
  if (tid >= NS * nch) return;
  int n = tid / nch, ch = tid % nch;
  float s, q, cnt;
  if (batchmode) {
    s = 0.f; q = 0.f;
    for (int m = 0; m < NS; ++m) { s += st[(m * nch + ch) * 2]; q += st[(m * nch + ch) * 2 + 1]; }
    cnt = (float)NS * (float)HW;
  } else {
    s = st[(n * nch + ch) * 2]; q = st[(n * nch + ch) * 2 + 1];
    cnt = (float)HW;
  }
  float mean = s / cnt;
  float var = q / cnt - mean * mean;
  float inv = rsqrtf(var + BNEPS);
  float av = gamma[ch] * inv;
  a[n * nch + ch] = av;
  b[n * nch + ch] = beta[ch] - mean * av;
}

// ---------------------------------------------------------------- stage 2 GEMM via MFMA
// grid (256, 5), block 256. Tile: 256 pix x 128 out, K=64.
// GAP=false: accumulate h2 sum/sumsq per (n,o). GAP=true: BN2+relu+GAP sums.
template<bool GAP>
__global__ __launch_bounds__(256, 2) void stage2_mfma_kernel(
    const unsigned short* __restrict__ h1,   // [5][HW][64] bf16
    const unsigned short* __restrict__ w2p,  // [2][2][128][32] bf16
    const float* __restrict__ a1g, const float* __restrict__ b1g,  // [5][64]
    const float* __restrict__ a2g, const float* __restrict__ b2g,  // [5][128]
    float* __restrict__ out)                 // [5][128][2] or [5][128]
{
  __shared__ __align__(16) unsigned short acts[256 * 64];
  __shared__ float red[4][128], redq[4][128];
  const int tid = threadIdx.x;
  const int lane = tid & 63, wave = tid >> 6;
  const int lanen = lane & 15, quad = lane >> 4;
  const int n = blockIdx.y;
  const int pix0 = blockIdx.x * 256;

  // ---- stage h1 tile with BN1+ReLU, fp32 math, repack bf16
  const int cg = tid & 7;
  float a1c[8], b1c[8];
#pragma unroll
  for (int j = 0; j < 8; ++j) {
    a1c[j] = a1g[n * 64 + cg * 8 + j];
    b1c[j] = b1g[n * 64 + cg * 8 + j];
  }
  const unsigned short* hb = h1 + ((size_t)n * HW + pix0) * 64;
#pragma unroll
  for (int it = 0; it < 8; ++it) {
    int idx = it * 256 + tid;
    int pix = idx >> 3;
    U16B in, o;
    in.v = *(const int4*)(hb + pix * 64 + cg * 8);
#pragma unroll
    for (int j = 0; j < 8; ++j) {
      float f = bf2f(in.s[j]);
      o.s[j] = (unsigned short)f2bf(fmaxf(a1c[j] * f + b1c[j], 0.f));
    }
    *(int4*)(acts + pix * 64 + cg * 8) = o.v;
  }
  __syncthreads();

  // ---- MFMA: per wave 4 mtiles x 8 ntiles
  f32x4 acc[4][8];
#pragma unroll
  for (int mt = 0; mt < 4; ++mt)
#pragma unroll
    for (int nt = 0; nt < 8; ++nt)
      acc[mt][nt] = (f32x4){0.f, 0.f, 0.f, 0.f};

#pragma unroll
  for (int ks = 0; ks < 2; ++ks) {
    bf16x8 af[4];
#pragma unroll
    for (int mt = 0; mt < 4; ++mt)
      af[mt] = *(const bf16x8*)(acts + (wave * 64 + mt * 16 + lanen) * 64 + ks * 32 + quad * 8);
#pragma unroll
    for (int hl = 0; hl < 2; ++hl) {
      const unsigned short* wb = w2p + (((ks * 2 + hl) * 128) + lanen) * 32 + quad * 8;
#pragma unroll
      for (int nt = 0; nt < 8; ++nt) {
        bf16x8 bf = *(const bf16x8*)(wb + nt * 16 * 32);
#pragma unroll
        for (int mt = 0; mt < 4; ++mt)
          acc[mt][nt] = __builtin_amdgcn_mfma_f32_16x16x32_bf16(af[mt], bf, acc[mt][nt], 0, 0, 0);
      }
    }
  }

  if constexpr (GAP) {
#pragma unroll
    for (int nt = 0; nt < 8; ++nt) {
      int o = nt * 16 + lanen;
      float a2v = a2g[n * DFEAT + o], b2v = b2g[n * DFEAT + o];
      float s = 0.f;
#pragma unroll
      for (int mt = 0; mt < 4; ++mt)
#pragma unroll
        for (int r = 0; r < 4; ++r)
          s += fmaxf(a2v * acc[mt][nt][r] + b2v, 0.f);
      s += __shfl_xor(s, 16); s += __shfl_xor(s, 32);
      if (lane < 16) red[wave][o] = s;
    }
    __syncthreads();
    if (tid < 128)
      atomicAdd(&out[n * DFEAT + tid], red[0][tid] + red[1][tid] + red[2][tid] + red[3][tid]);
  } else {
#pragma unroll
    for (int nt = 0; nt < 8; ++nt) {
      int o = nt * 16 + lanen;
      float s = 0.f, q = 0.f;
#pragma unroll
      for (int mt = 0; mt < 4; ++mt)
#pragma unroll
        for (int r = 0; r < 4; ++r) {
          float v = acc[mt][nt][r];
          s += v; q += v * v;
        }
      s += __shfl_xor(s, 16); s += __shfl_xor(s, 32);
      q += __shfl_xor(q, 16); q += __shfl_xor(q, 32);
      if (lane < 16) { red[wave][o] = s; redq[wave][o] = q; }
    }
    __syncthreads();
    if (tid < 128) {
      atomicAdd(&out[(n * DFEAT + tid) * 2 + 0], red[0][tid] + red[1][tid] + red[2][tid] + red[3][tid]);
      atomicAdd(&out[(n * DFEAT + tid) * 2 + 1], redq[0][tid] + redq[1][tid] + redq[2][tid] + redq[3][tid]);
    }
  }
}

// ---------------------------------------------------------------- feature normalize
__global__ void feat_kernel(const float* __restrict__ gap, float* __restrict__ QK) {
  int b = blockIdx.x;
  int e = b / 5, n = b % 5;
  int g = e >> 1, br = e & 1;
  int d = threadIdx.x;
  float v = gap[(e * 5 + n) * DFEAT + d] * (1.0f / (float)HW);
  float q = v * v;
  for (int off = 32; off; off >>= 1) q += __shfl_down(q, off, 64);
  __shared__ float r2[2];
  if ((d & 63) == 0) r2[d >> 6] = q;
  __syncthreads();
  float nrm = sqrtf(r2[0] + r2[1]);
  float inv = 1.0f / fmaxf(nrm, 1e-12f);
  QK[((br * 3 + g) * 5 + n) * DFEAT + d] = v * inv;
}

// ---------------------------------------------------------------- final loss
__global__ __launch_bounds__(256) void loss_kernel(const float* __restrict__ QK,
                                                   const int* __restrict__ dm,
                                                   float* __restrict__ out)
{
  __shared__ float Qs[1920], Ks[1920];
  __shared__ float S[75], X[45], cnt[15], ltab[15];
  const int tid = threadIdx.x;
  for (int i = tid; i < 1920; i += 256) { Qs[i] = QK[i]; Ks[i] = QK[1920 + i]; }
  if (tid < 15) cnt[tid] = 0.f;
  __syncthreads();
  if (tid < 75) {
    int g = tid / 25, i = (tid / 5) % 5, j = tid % 5;
    const float* q = &Qs[(g * 5 + i) * 128];
    const float* k = &Ks[(g * 5 + j) * 128];
    float s = 0.f;
    for (int d = 0; d < 128; ++d) s += q[d] * k[d];
    S[tid] = s;
  } else if (tid < 120) {
    int u = tid - 75;
    int g = u / 15, i = (u % 15) / 3, h = u % 3;
    const float* q = &Qs[(g * 5 + i) * 128];
    const float* k = &Ks[(h * 5 + i) * 128];
    float s = 0.f;
    for (int d = 0; d < 128; ++d) s += q[d] * k[d];
    X[u] = s;
  }
  {
    int a = tid >> 6, l = tid & 63;
    int c0 = 0, c1 = 0, c2 = 0;
    const int* base = dm + a * 16384;
    for (int k = 0; k < 256; ++k) {
      int v = base[k * 64 + l];
      c0 += (v == 1); c1 += (v == 2); c2 += (v == 3);
    }
    atomicAdd(&cnt[0 * 5 + a + 1], (float)c0);
    atomicAdd(&cnt[1 * 5 + a + 1], (float)c1);
    atomicAdd(&cnt[2 * 5 + a + 1], (float)c2);
  }
  __syncthreads();
  if (tid < 15) {
    int g = tid / 5, i = tid % 5;
    const float inv_t = 1.0f / TEMPER;
    float lg[9];
    lg[0] = S[g * 25 + i * 5 + i] * inv_t;
    for (int j = 0; j < 5; ++j) lg[1 + j] = (j == i) ? (-1e9f * inv_t) : S[g * 25 + i * 5 + j] * inv_t;
    for (int h = 0; h < 3; ++h) lg[6 + h] = (h == g) ? (-1e9f * inv_t) : X[g * 15 + i * 3 + h] * inv_t;
    float m = lg[0];
    for (int k = 1; k < 9; ++k) m = fmaxf(m, lg[k]);
    float se = 0.f;
    for (int k = 0; k < 9; ++k) se += expf(lg[k] - m);
    ltab[tid] = -lg[0] + m + logf(se);
  }
  __syncthreads();
  if (tid == 0) {
    float tot = 0.f, acc = 0.f;
    for (int k = 0; k < 15; ++k) { tot += cnt[k]; acc += cnt[k] * ltab[k]; }
    out[0] = (tot > 0.f) ? acc / fmaxf(tot, 1.f) : 0.f;
  }
}

// ---------------------------------------------------------------- host orchestration
extern "C" void kernel_launch(void* const* d_in, const int* in_sizes, int n_in,
                              void* d_out, int out_size, void* d_ws, size_t ws_size,
                              hipStream_t stream) {
  (void)in_sizes; (void)n_in; (void)out_size; (void)ws_size;

  const float* sp[3]  = {(const float*)d_in[0],  (const float*)d_in[8],  (const float*)d_in[16]};
  const float* dn[3]  = {(const float*)d_in[1],  (const float*)d_in[9],  (const float*)d_in[17]};
  const float* w1[3]  = {(const float*)d_in[2],  (const float*)d_in[10], (const float*)d_in[18]};
  const float* gm1[3] = {(const float*)d_in[3],  (const float*)d_in[11], (const float*)d_in[19]};
  const float* bt1[3] = {(const float*)d_in[4],  (const float*)d_in[12], (const float*)d_in[20]};
  const float* w2[3]  = {(const float*)d_in[5],  (const float*)d_in[13], (const float*)d_in[21]};
  const float* gm2[3] = {(const float*)d_in[6],  (const float*)d_in[14], (const float*)d_in[22]};
  const float* bt2[3] = {(const float*)d_in[7],  (const float*)d_in[15], (const float*)d_in[23]};
  const int*   dm     = (const int*)d_in[24];

  float* ws_f = (float*)d_ws;
  unsigned short* h1u  = (unsigned short*)ws_f;                       // [5][HW][64] bf16 = 10,485,760 f
  unsigned short* xTu  = (unsigned short*)(ws_f + 10485760);          // [5][HW][<=64] bf16
  unsigned short* w1pu = (unsigned short*)(ws_f + 20971520);          // <= 73728 bf16 = 36864 f
  unsigned short* w2pu = (unsigned short*)(ws_f + 20971520 + 36864);  // 16384 bf16 = 8192 f
  float* st1 = ws_f + 20971520 + 36864 + 8192;  // 640
  float* st2 = st1 + 640;                       // 1280 (contiguous with st1 for zeroing)
  float* a1  = st2 + 1280;                      // 320
  float* b1  = a1 + 320;
  float* a2  = b1 + 320;                        // 640
  float* b2  = a2 + 640;
  float* gap = b2 + 640;                        // [6][640]
  float* QK  = gap + 3840;                      // 3840

  zero_kernel<<<15, 256, 0, stream>>>(gap, 3840);

  for (int g = 0; g < 3; ++g) {
    // weight prep once per granularity
    if (g == 0)      wprep_kernel<64, 64><<<(9*2*2*64*32 + 16384 + 255)/256, 256, 0, stream>>>(w1[g], w2[g], w1pu, w2pu);
    else if (g == 1) wprep_kernel<32, 32><<<(9*1*2*64*32 + 16384 + 255)/256, 256, 0, stream>>>(w1[g], w2[g], w1pu, w2pu);
    else             wprep_kernel<16, 32><<<(9*1*2*64*32 + 16384 + 255)/256, 256, 0, stream>>>(w1[g], w2[g], w1pu, w2pu);

    for (int br = 0; br < 2; ++br) {
      const int e = g * 2 + br;
      const float* x = br ? dn[g] : sp[g];

      if (g == 0)      transpose_kernel<64, 64><<<dim3(1024, 5), 256, 0, stream>>>(x, xTu);
      else if (g == 1) transpose_kernel<32, 32><<<dim3(1024, 5), 256, 0, stream>>>(x, xTu);
      else             transpose_kernel<16, 32><<<dim3(1024, 5), 256, 0, stream>>>(x, xTu);

      zero_kernel<<<8, 256, 0, stream>>>(st1, 1920);   // st1 (640) + st2 (1280)

      if (g == 0) conv_mfma_kernel<64><<<dim3(8, 32, 5), 256, 0, stream>>>(xTu, w1pu, h1u, st1);
      else        conv_mfma_kernel<32><<<dim3(8, 32, 5), 256, 0, stream>>>(xTu, w1pu, h1u, st1);

      bn_param_kernel<<<1, 320, 0, stream>>>(st1, gm1[g], bt1[g], a1, b1, CMID, br);
      stage2_mfma_kernel<false><<<dim3(256, 5), 256, 0, stream>>>(h1u, w2pu, a1, b1, nullptr, nullptr, st2);
      bn_param_kernel<<<1, 640, 0, stream>>>(st2, gm2[g], bt2[g], a2, b2, DFEAT, br);
      stage2_mfma_kernel<true><<<dim3(256, 5), 256, 0, stream>>>(h1u, w2pu, a1, b1, a2, b2, gap + e * 640);
    }
  }

  feat_kernel<<<30, 128, 0, stream>>>(gap, QK);
  loss_kernel<<<1, 256, 0, stream>>>(QK, dm, (float*)d_out);
}